// Round 15
// baseline (177.867 us; speedup 1.0000x reference)
//
#include <hip/hip_runtime.h>
#include <stdint.h>

// int4 grouped-quant GEMM: out[64][28672] = x[64][8192] . W^T + bias
// W packed [N][K/2] int32, one byte/int32 = 2 nibbles (low = even k), zp = 8,
// per-128-k scales. fp16 ref -> harness gives x/scales/bias/out as FP32.
// Round-15: PERFECT GRID BALANCE. 28672 = 256 x 112 -> 256 blocks (exactly
// 1/CU, 32/XCD). R11/R14 components unchanged: kstep-split waves, X-in-regs
// (distance-1), involution-swizzled W staging via global_load_lds, counted
// vmcnt (never 0), scales pre-transposed + reg-prefetched. Removes the
// 448-on-256 integer imbalance (+14%) that survived all scheduling rounds.

typedef __attribute__((ext_vector_type(8))) short     short8;
typedef __attribute__((ext_vector_type(4))) float     f32x4;
typedef __attribute__((ext_vector_type(4))) int       i32x4;
typedef __attribute__((ext_vector_type(2))) _Float16  f16x2;
typedef __attribute__((ext_vector_type(8))) _Float16  f16x8;

// async global->LDS, 16 B/lane. LDS dest = wave-uniform base + lane*16 (HW);
// global source is PER-LANE -> swizzle via pre-swizzled source (m173).
static __device__ __forceinline__ void gload_lds16(const void* gp, void* lp) {
    __builtin_amdgcn_global_load_lds(
        (const __attribute__((address_space(1))) unsigned int*)gp,
        (__attribute__((address_space(3))) unsigned int*)lp, 16, 0, 0);
}

// int4 pair -> fp16 pair: u = 0x6400|nib (fp16 1024+v, exact), (u-1032) exact
// in f16 (= v-8), then *s (single rounding - matches reference fp16 mul).
static __device__ __forceinline__ f16x8 dequant(const i32x4& w, f16x2 s2) {
    const f16x2 c1032 = {(_Float16)1032.0f, (_Float16)1032.0f};
    union { unsigned u[4]; f16x8 v; } r;
    #pragma unroll
    for (int j = 0; j < 4; ++j) {
        unsigned v = (unsigned)w[j];
        unsigned u = ((v & 0xFu) | 0x64006400u) | ((v << 12) & 0xF0000u);
        f16x2 h = __builtin_bit_cast(f16x2, u);
        h = (h - c1032) * s2;
        r.u[j] = __builtin_bit_cast(unsigned, h);
    }
    return r.v;
}

// x fp32 [64][K] -> fp16 (lossless) in A-fragment order: xf[g][st][mt][lane][8]
__global__ __launch_bounds__(256)
void xpack_kernel(const float* __restrict__ x, unsigned short* __restrict__ xf, int K) {
    int c    = blockIdx.x * 256 + threadIdx.x;
    int g    = c >> 10;
    int st   = (c >> 8) & 3;
    int mt   = (c >> 6) & 3;
    int lane = c & 63;
    int quad = lane >> 4, l15 = lane & 15;
    const float* p = x + (size_t)(l15 + mt * 16) * K + g * 128 + st * 32 + quad * 8;
    f32x4 lo = *(const f32x4*)p;
    f32x4 hi = *(const f32x4*)(p + 4);
    f16x8 r = { (_Float16)lo[0], (_Float16)lo[1], (_Float16)lo[2], (_Float16)lo[3],
                (_Float16)hi[0], (_Float16)hi[1], (_Float16)hi[2], (_Float16)hi[3] };
    *(short8*)(xf + (size_t)c * 8) = __builtin_bit_cast(short8, r);
}

// scales [N][ng] -> [ng][N] (write-coalesced)
__global__ __launch_bounds__(256)
void strans_kernel(const float* __restrict__ sc, float* __restrict__ sct, int N, int ng) {
    int n = blockIdx.x * 256 + threadIdx.x;
    int g = blockIdx.y;
    sct[(size_t)g * N + n] = sc[(size_t)n * ng + g];
}

__global__ __launch_bounds__(256, 1)
void int4mm_kernel(const unsigned short* __restrict__ xf,  // fp16 frag-ordered x
                   const int*   __restrict__ wp,           // [N][K/2]
                   const float* __restrict__ sct,          // [ng][N]
                   const float* __restrict__ bias,         // [N]
                   float*       __restrict__ out,          // [64][N]
                   int K, int N)
{
    __shared__ char lds[57344];              // 2 x 28 KB W dbuf (epilogue reuses)

    const int tid  = threadIdx.x;
    const int lane = tid & 63;
    const int wave = tid >> 6;               // kstep owner: k-quarter of each group
    const int quad = lane >> 4;
    const int l15  = lane & 15;
    const int blk  = blockIdx.x * 112;
    const int ng   = K / 128;                // 64 groups

    const char* wp8 = (const char*)wp;       // one col's W row = 16384 B

    // W stage sources (verified involution family): instr j (0..6) of wave w
    // covers local cols cloc = (w*7+j)*4 + quad; lane supplies global chunk
    // l15 ^ (cloc&15); LDS slot s of col c ends up holding chunk s^(c&15).
    unsigned woff[7];
    #pragma unroll
    for (int j = 0; j < 7; ++j) {
        const int cloc  = (wave * 7 + j) * 4 + quad;
        const int chunk = l15 ^ (cloc & 15);
        woff[j] = ((unsigned)(blk + cloc) << 14) + ((unsigned)chunk << 4);
    }

    // B-frag ds_read: col c = nt*16+l15, chunk q = wave*4+quad at slot q^l15
    // -> beat-optimal (verified R11/R14 family).
    const int q = wave * 4 + quad;
    int rdW[7];
    #pragma unroll
    for (int nt = 0; nt < 7; ++nt)
        rdW[nt] = (nt * 16 + l15) * 256 + ((q ^ l15) << 4);

    // ---- prologue: X(0) + sc(0) + stage W(0) -> buf0 ----
    const char* xbase = (const char*)xf + wave * 4096 + lane * 16;
    f16x8 xn[4], xc[4];
    #pragma unroll
    for (int mt = 0; mt < 4; ++mt)
        xn[mt] = *(const f16x8*)(xbase + mt * 1024);

    float sfn[7], sfu[7];
    #pragma unroll
    for (int nt = 0; nt < 7; ++nt)
        sfn[nt] = sct[blk + nt * 16 + l15];  // g = 0

    #pragma unroll
    for (int j = 0; j < 7; ++j)
        gload_lds16(wp8 + woff[j], lds + (wave * 7 + j) * 1024);

    f32x4 acc[4][7];
    #pragma unroll
    for (int mt = 0; mt < 4; ++mt)
        #pragma unroll
        for (int nt = 0; nt < 7; ++nt)
            acc[mt][nt] = f32x4{0.f, 0.f, 0.f, 0.f};

    // Main loop. Per-iter VMEM = 4 X + 7 sc + 7 W = 18, all fenced between
    // the two memory-clobber asms -> at vmcnt(18) the 18 newest are exactly
    // this iter's loads; in-order retirement forces W(g) (older) complete
    // while X(g+1)/sc(g+1)/W(g+1) stay in flight across both barriers.
    #pragma unroll 1
    for (int g = 0; g < ng; ++g) {
        const int p  = g & 1;
        const int gn = (g + 1 < ng) ? g + 1 : ng - 1;   // clamped dead tail

        #pragma unroll
        for (int mt = 0; mt < 4; ++mt) xc[mt] = xn[mt]; // consume X(g)
        const char* xs = xbase + (size_t)gn * 16384;    // issue X(g+1)
        #pragma unroll
        for (int mt = 0; mt < 4; ++mt)
            xn[mt] = *(const f16x8*)(xs + mt * 1024);

        #pragma unroll
        for (int nt = 0; nt < 7; ++nt) sfu[nt] = sfn[nt];
        const float* sp = sct + (size_t)gn * N + blk;   // issue sc(g+1)
        #pragma unroll
        for (int nt = 0; nt < 7; ++nt)
            sfn[nt] = sp[nt * 16 + l15];

        __builtin_amdgcn_s_barrier();        // iter g-1 readers of buf[p^1] done

        #pragma unroll
        for (int j = 0; j < 7; ++j)          // stage W(g+1) -> buf[p^1]
            gload_lds16(wp8 + woff[j] + (size_t)gn * 256,
                        lds + (p ^ 1) * 28672 + (wave * 7 + j) * 1024);

        asm volatile("s_waitcnt vmcnt(18)" ::: "memory");  // W(g) landed
        __builtin_amdgcn_s_barrier();
        __builtin_amdgcn_sched_barrier(0);   // keep ds_reads below the sync

        const char* wb = lds + p * 28672;
        #pragma unroll
        for (int nt = 0; nt < 7; ++nt) {
            i32x4 v = *(const i32x4*)(wb + rdW[nt]);
            f16x8 b = dequant(v, f16x2{(_Float16)sfu[nt], (_Float16)sfu[nt]});
            #pragma unroll
            for (int mt = 0; mt < 4; ++mt)
                acc[mt][nt] = __builtin_amdgcn_mfma_f32_16x16x32_f16(
                                  xc[mt], b, acc[mt][nt], 0, 0, 0);
        }
    }

    // ---- epilogue: cross-wave (kstep) reduce, two rounds (LDS = 56 KB). ----
    // Wave w owns mt = w. Round A: nt 0..3 (48 KB); round B: nt 4..6 (36 KB).
    __syncthreads();
    #pragma unroll
    for (int o = 0; o < 4; ++o) {            // round A writes
        if (o == wave) continue;             // wave-uniform branch
        const int s = wave - (wave > o ? 1 : 0);
        #pragma unroll
        for (int ia = 0; ia < 4; ++ia)
            *(f32x4*)(lds + (size_t)(((o * 3 + s) * 4 + ia) * 1024) + lane * 16)
                = acc[o][ia];
    }
    __syncthreads();
    #pragma unroll
    for (int ia = 0; ia < 4; ++ia) {
        f32x4 own = acc[0][ia];              // wave-uniform compile-time select
        if (wave == 1) own = acc[1][ia];
        if (wave == 2) own = acc[2][ia];
        if (wave == 3) own = acc[3][ia];
        #pragma unroll
        for (int s = 0; s < 3; ++s)
            own += *(const f32x4*)(lds + (size_t)(((wave * 3 + s) * 4 + ia) * 1024)
                                   + lane * 16);
        const int col = blk + ia * 16 + l15;
        const float bv = bias[col];
        #pragma unroll
        for (int r = 0; r < 4; ++r)
            out[(size_t)(wave * 16 + quad * 4 + r) * N + col] = own[r] + bv;
    }
    __syncthreads();
    #pragma unroll
    for (int o = 0; o < 4; ++o) {            // round B writes
        if (o == wave) continue;
        const int s = wave - (wave > o ? 1 : 0);
        #pragma unroll
        for (int ib = 0; ib < 3; ++ib)
            *(f32x4*)(lds + (size_t)(((o * 3 + s) * 3 + ib) * 1024) + lane * 16)
                = acc[o][4 + ib];
    }
    __syncthreads();
    #pragma unroll
    for (int ib = 0; ib < 3; ++ib) {
        f32x4 own = acc[0][4 + ib];
        if (wave == 1) own = acc[1][4 + ib];
        if (wave == 2) own = acc[2][4 + ib];
        if (wave == 3) own = acc[3][4 + ib];
        #pragma unroll
        for (int s = 0; s < 3; ++s)
            own += *(const f32x4*)(lds + (size_t)(((wave * 3 + s) * 3 + ib) * 1024)
                                   + lane * 16);
        const int col = blk + (4 + ib) * 16 + l15;
        const float bv = bias[col];
        #pragma unroll
        for (int r = 0; r < 4; ++r)
            out[(size_t)(wave * 16 + quad * 4 + r) * N + col] = own[r] + bv;
    }
}

extern "C" void kernel_launch(void* const* d_in, const int* in_sizes, int n_in,
                              void* d_out, int out_size, void* d_ws, size_t ws_size,
                              hipStream_t stream)
{
    const float* x    = (const float*)d_in[0];
    const int*   wp   = (const int*)d_in[1];
    const float* sc   = (const float*)d_in[2];
    const float* bias = (const float*)d_in[3];
    float*       out  = (float*)d_out;

    const int N  = in_sizes[3];                       // 28672
    const long long Kh = (long long)in_sizes[1] / N;  // 4096
    const int K  = (int)(2 * Kh);                     // 8192
    const int ng = K / 128;                           // 64

    unsigned short* xf = (unsigned short*)d_ws;       // 1 MB frag-ordered fp16 x
    const size_t xf_bytes = (size_t)ng * 16384;
    float* sct = (float*)((char*)d_ws + xf_bytes);    // 7.3 MB transposed scales

    xpack_kernel<<<(ng * 1024) / 256, 256, 0, stream>>>(x, xf, K);
    strans_kernel<<<dim3(N / 256, ng), 256, 0, stream>>>(sc, sct, N, ng);
    int4mm_kernel<<<N / 112, 256, 0, stream>>>(xf, wp, sct, bias, out, K, N);
}

// Round 16
// 136.983 us; speedup vs baseline: 1.2985x; 1.2985x over previous
//
#include <hip/hip_runtime.h>
#include <stdint.h>

// int4 grouped-quant GEMM: out[64][28672] = x[64][8192] . W^T + bias
// W packed [N][K/2] int32, one byte/int32 = 2 nibbles (low = even k), zp = 8,
// per-128-k scales. fp16 ref -> harness gives x/scales/bias/out as FP32.
// Round-16: PIPELINE COUNT. Per-block W delivery is invariant ~10 GB/s across
// sync/depth/granule/width (R8-R15) -> aggregate = nblocks x 10 GB/s. R11's
// 448 blocks = 4.4 TB/s. Now 896 x 32-col blocks (~3.5-4/CU resident, 24 KB
// LDS, <=128 VGPR): 2x pipelines, X overhead bounded (xf is L2-resident).
// Structure otherwise identical to R11 (kstep-split waves, X-in-regs,
// involution-swizzled W staging, counted vmcnt never 0).

typedef __attribute__((ext_vector_type(8))) short     short8;
typedef __attribute__((ext_vector_type(4))) float     f32x4;
typedef __attribute__((ext_vector_type(4))) int       i32x4;
typedef __attribute__((ext_vector_type(2))) _Float16  f16x2;
typedef __attribute__((ext_vector_type(8))) _Float16  f16x8;

// async global->LDS, 16 B/lane. LDS dest = wave-uniform base + lane*16 (HW);
// global source is PER-LANE -> swizzle via pre-swizzled source (m173).
static __device__ __forceinline__ void gload_lds16(const void* gp, void* lp) {
    __builtin_amdgcn_global_load_lds(
        (const __attribute__((address_space(1))) unsigned int*)gp,
        (__attribute__((address_space(3))) unsigned int*)lp, 16, 0, 0);
}

// int4 pair -> fp16 pair: u = 0x6400|nib (fp16 1024+v, exact), (u-1032) exact
// in f16 (= v-8), then *s (single rounding - matches reference fp16 mul).
static __device__ __forceinline__ f16x8 dequant(const i32x4& w, f16x2 s2) {
    const f16x2 c1032 = {(_Float16)1032.0f, (_Float16)1032.0f};
    union { unsigned u[4]; f16x8 v; } r;
    #pragma unroll
    for (int j = 0; j < 4; ++j) {
        unsigned v = (unsigned)w[j];
        unsigned u = ((v & 0xFu) | 0x64006400u) | ((v << 12) & 0xF0000u);
        f16x2 h = __builtin_bit_cast(f16x2, u);
        h = (h - c1032) * s2;
        r.u[j] = __builtin_bit_cast(unsigned, h);
    }
    return r.v;
}

// x fp32 [64][K] -> fp16 (lossless) in A-fragment order: xf[g][st][mt][lane][8]
__global__ __launch_bounds__(256)
void xpack_kernel(const float* __restrict__ x, unsigned short* __restrict__ xf, int K) {
    int c    = blockIdx.x * 256 + threadIdx.x;
    int g    = c >> 10;
    int st   = (c >> 8) & 3;
    int mt   = (c >> 6) & 3;
    int lane = c & 63;
    int quad = lane >> 4, l15 = lane & 15;
    const float* p = x + (size_t)(l15 + mt * 16) * K + g * 128 + st * 32 + quad * 8;
    f32x4 lo = *(const f32x4*)p;
    f32x4 hi = *(const f32x4*)(p + 4);
    f16x8 r = { (_Float16)lo[0], (_Float16)lo[1], (_Float16)lo[2], (_Float16)lo[3],
                (_Float16)hi[0], (_Float16)hi[1], (_Float16)hi[2], (_Float16)hi[3] };
    *(short8*)(xf + (size_t)c * 8) = __builtin_bit_cast(short8, r);
}

__global__ __launch_bounds__(256, 4)
void int4mm_kernel(const unsigned short* __restrict__ xf,  // fp16 frag-ordered x
                   const int*   __restrict__ wp,           // [N][K/2]
                   const float* __restrict__ sc,           // [N][ng]
                   const float* __restrict__ bias,         // [N]
                   float*       __restrict__ out,          // [64][N]
                   int K, int N)
{
    __shared__ char lds[24576];              // 16 KB W dbuf | 8 KB scales
    char*  ldsW = lds;                       // [2][32 col][16 slot][16 B]
    float* ldsS = (float*)(lds + 16384);     // [64 g][32 col]
    // (epilogue reuses all 24 KB for cross-wave partials)

    const int tid  = threadIdx.x;
    const int lane = tid & 63;
    const int wave = tid >> 6;               // kstep owner: k-quarter of each group
    const int quad = lane >> 4;
    const int l15  = lane & 15;
    const int blk32 = blockIdx.x * 32;
    const int ng   = K / 128;                // 64 groups

    const char* wp8 = (const char*)wp;       // one col's W row = 16384 B

    // W stage sources (R11-verified involution): instr j (0..1) of wave w
    // covers local cols cloc = (w*2+j)*4 + quad; lane supplies global chunk
    // l15 ^ (cloc&15); LDS slot s of col c ends up holding chunk s^(c&15).
    unsigned woff[2];
    #pragma unroll
    for (int j = 0; j < 2; ++j) {
        const int cloc  = (wave * 2 + j) * 4 + quad;
        const int chunk = l15 ^ (cloc & 15);
        woff[j] = ((unsigned)(blk32 + cloc) << 14) + ((unsigned)chunk << 4);
    }

    // B-frag ds_read: col c = nt*16+l15, chunk q = wave*4+quad at slot q^l15
    // -> beat-optimal (verified R11/R14 family).
    const int q = wave * 4 + quad;
    int rdW[2];
    #pragma unroll
    for (int nt = 0; nt < 2; ++nt)
        rdW[nt] = (nt * 16 + l15) * 256 + ((q ^ l15) << 4);

    // ---- prologue ----
    // scales: ldsS[g][c] = sc[(blk32+c)*ng + g]; 2 f32x4 per thread.
    {
        const int c  = tid & 31;
        const int g0 = (tid >> 5) * 8;       // 8 thread-rows x 8 groups = 64
        const float* sp = sc + (size_t)(blk32 + c) * ng + g0;
        f32x4 s0 = *(const f32x4*)(sp);
        f32x4 s1 = *(const f32x4*)(sp + 4);
        #pragma unroll
        for (int j = 0; j < 4; ++j) {
            ldsS[(g0 + j) * 32 + c]     = s0[j];
            ldsS[(g0 + 4 + j) * 32 + c] = s1[j];
        }
    }
    #pragma unroll
    for (int j = 0; j < 2; ++j)              // stage W(0) -> buf0
        gload_lds16(wp8 + woff[j], ldsW + (wave * 2 + j) * 1024);

    const char* xbase = (const char*)xf + wave * 4096 + lane * 16;
    f16x8 xn[4], xc[4];
    #pragma unroll
    for (int mt = 0; mt < 4; ++mt)           // X(0) -> regs
        xn[mt] = *(const f16x8*)(xbase + mt * 1024);

    f32x4 acc[4][2];
    #pragma unroll
    for (int mt = 0; mt < 4; ++mt)
        #pragma unroll
        for (int nt = 0; nt < 2; ++nt)
            acc[mt][nt] = f32x4{0.f, 0.f, 0.f, 0.f};

    __syncthreads();   // prologue drain: scales + W(0) + X(0) landed

    // Main loop. Per-iter VMEM = 4 X + 2 W = 6, fenced between the two
    // memory-clobber asms. At vmcnt(6): the 6 newest = {X(g+1), W(g+1)} stay
    // in flight; W(g) (issued last iter) is forced complete by in-order
    // retirement. X(g) additionally guarded by the compiler's own waits.
    #pragma unroll 1
    for (int g = 0; g < ng; ++g) {
        const int p  = g & 1;
        const int gn = (g + 1 < ng) ? g + 1 : ng - 1;   // clamped dead tail

        #pragma unroll
        for (int mt = 0; mt < 4; ++mt) xc[mt] = xn[mt]; // consume X(g)
        const char* xs = xbase + (size_t)gn * 16384;    // issue X(g+1)
        #pragma unroll
        for (int mt = 0; mt < 4; ++mt)
            xn[mt] = *(const f16x8*)(xs + mt * 1024);

        __builtin_amdgcn_s_barrier();        // iter g-1 readers of buf[p^1] done

        #pragma unroll
        for (int j = 0; j < 2; ++j)          // stage W(g+1) -> buf[p^1]
            gload_lds16(wp8 + woff[j] + (size_t)gn * 256,
                        ldsW + (p ^ 1) * 8192 + (wave * 2 + j) * 1024);

        asm volatile("s_waitcnt vmcnt(6)" ::: "memory");  // W(g) landed (mine)
        __builtin_amdgcn_s_barrier();                     // ...for all waves
        __builtin_amdgcn_sched_barrier(0);   // keep ds_reads below the sync

        const char* wb = ldsW + p * 8192;
        const float* sg = ldsS + g * 32;

        #pragma unroll
        for (int nt = 0; nt < 2; ++nt) {
            i32x4 v = *(const i32x4*)(wb + rdW[nt]);
            const float sf = sg[nt * 16 + l15];
            f16x8 b = dequant(v, f16x2{(_Float16)sf, (_Float16)sf});
            #pragma unroll
            for (int mt = 0; mt < 4; ++mt)
                acc[mt][nt] = __builtin_amdgcn_mfma_f32_16x16x32_f16(
                                  xc[mt], b, acc[mt][nt], 0, 0, 0);
        }
    }

    // ---- epilogue: cross-wave (kstep) reduce. Wave w owns mt = w. ----
    // Partials: addr(owner o, slot s, nt) = ((o*3+s)*2+nt)*1024 + lane*16 (24 KB).
    __syncthreads();
    #pragma unroll
    for (int o = 0; o < 4; ++o) {
        if (o == wave) continue;             // wave-uniform branch
        const int s = wave - (wave > o ? 1 : 0);
        #pragma unroll
        for (int nt = 0; nt < 2; ++nt)
            *(f32x4*)(lds + (size_t)(((o * 3 + s) * 2 + nt) * 1024) + lane * 16)
                = acc[o][nt];
    }
    __syncthreads();

    f32x4 own[2];
    #pragma unroll
    for (int nt = 0; nt < 2; ++nt) own[nt] = acc[0][nt];
    #pragma unroll
    for (int o = 1; o < 4; ++o)
        if (wave == o) {                     // wave-uniform, compile-time idx
            own[0] = acc[o][0]; own[1] = acc[o][1];
        }
    #pragma unroll
    for (int s = 0; s < 3; ++s)
        #pragma unroll
        for (int nt = 0; nt < 2; ++nt)
            own[nt] += *(const f32x4*)(lds + (size_t)(((wave * 3 + s) * 2 + nt) * 1024)
                                       + lane * 16);

    #pragma unroll
    for (int nt = 0; nt < 2; ++nt) {
        const int col = blk32 + nt * 16 + l15;
        const float bv = bias[col];
        #pragma unroll
        for (int r = 0; r < 4; ++r)
            out[(size_t)(wave * 16 + quad * 4 + r) * N + col] = own[nt][r] + bv;
    }
}

extern "C" void kernel_launch(void* const* d_in, const int* in_sizes, int n_in,
                              void* d_out, int out_size, void* d_ws, size_t ws_size,
                              hipStream_t stream)
{
    const float* x    = (const float*)d_in[0];
    const int*   wp   = (const int*)d_in[1];
    const float* sc   = (const float*)d_in[2];
    const float* bias = (const float*)d_in[3];
    float*       out  = (float*)d_out;

    const int N  = in_sizes[3];                       // 28672
    const long long Kh = (long long)in_sizes[1] / N;  // 4096
    const int K  = (int)(2 * Kh);                     // 8192
    const int ng = K / 128;                           // 64

    unsigned short* xf = (unsigned short*)d_ws;       // 1 MB frag-ordered fp16 x

    xpack_kernel<<<(ng * 1024) / 256, 256, 0, stream>>>(x, xf, K);
    int4mm_kernel<<<N / 32, 256, 0, stream>>>(xf, wp, sc, bias, out, K, N);
}

// Round 18
// 131.596 us; speedup vs baseline: 1.3516x; 1.0409x over previous
//
#include <hip/hip_runtime.h>
#include <stdint.h>

// int4 grouped-quant GEMM: out[64][28672] = x[64][8192] . W^T + bias
// W packed [N][K/2] int32, one byte/int32 = 2 nibbles (low = even k), zp = 8,
// per-128-k scales. fp16 ref -> harness gives x/scales/bias/out as FP32.
// Round-18: R17 producer/consumer with the FLAG RACE FIXED: atomic flag adds
// were per-lane (+64/wave), opening gates after 1/4 producers; now lane-0-
// gated (+1/wave, threshold 4). Waves 0-3 stream W into a 4-slot LDS ring
// (2 groups in flight, vmcnt-counted), waves 4-7 consume (kstep-split, as
// R11); zero barriers in the main loop.

typedef __attribute__((ext_vector_type(8))) short     short8;
typedef __attribute__((ext_vector_type(4))) float     f32x4;
typedef __attribute__((ext_vector_type(4))) int       i32x4;
typedef __attribute__((ext_vector_type(2))) _Float16  f16x2;
typedef __attribute__((ext_vector_type(8))) _Float16  f16x8;

#define RING 4

// async global->LDS, 16 B/lane. LDS dest = wave-uniform base + lane*16 (HW);
// global source is PER-LANE -> swizzle via pre-swizzled source (m173).
static __device__ __forceinline__ void gload_lds16(const void* gp, void* lp) {
    __builtin_amdgcn_global_load_lds(
        (const __attribute__((address_space(1))) unsigned int*)gp,
        (__attribute__((address_space(3))) unsigned int*)lp, 16, 0, 0);
}

// int4 pair -> fp16 pair: u = 0x6400|nib (fp16 1024+v, exact), (u-1032) exact
// in f16 (= v-8), then *s (single rounding - matches reference fp16 mul).
static __device__ __forceinline__ f16x8 dequant(const i32x4& w, f16x2 s2) {
    const f16x2 c1032 = {(_Float16)1032.0f, (_Float16)1032.0f};
    union { unsigned u[4]; f16x8 v; } r;
    #pragma unroll
    for (int j = 0; j < 4; ++j) {
        unsigned v = (unsigned)w[j];
        unsigned u = ((v & 0xFu) | 0x64006400u) | ((v << 12) & 0xF0000u);
        f16x2 h = __builtin_bit_cast(f16x2, u);
        h = (h - c1032) * s2;
        r.u[j] = __builtin_bit_cast(unsigned, h);
    }
    return r.v;
}

// one-per-wave flag signal (lane 0 only), workgroup-scope release
static __device__ __forceinline__ void signal1(int* f, int lane) {
    if (lane == 0)
        __hip_atomic_fetch_add(f, 1, __ATOMIC_RELEASE, __HIP_MEMORY_SCOPE_WORKGROUP);
}

// x fp32 [64][K] -> fp16 (lossless) in A-fragment order: xf[g][st][mt][lane][8]
__global__ __launch_bounds__(256)
void xpack_kernel(const float* __restrict__ x, unsigned short* __restrict__ xf, int K) {
    int c    = blockIdx.x * 256 + threadIdx.x;
    int g    = c >> 10;
    int st   = (c >> 8) & 3;
    int mt   = (c >> 6) & 3;
    int lane = c & 63;
    int quad = lane >> 4, l15 = lane & 15;
    const float* p = x + (size_t)(l15 + mt * 16) * K + g * 128 + st * 32 + quad * 8;
    f32x4 lo = *(const f32x4*)p;
    f32x4 hi = *(const f32x4*)(p + 4);
    f16x8 r = { (_Float16)lo[0], (_Float16)lo[1], (_Float16)lo[2], (_Float16)lo[3],
                (_Float16)hi[0], (_Float16)hi[1], (_Float16)hi[2], (_Float16)hi[3] };
    *(short8*)(xf + (size_t)c * 8) = __builtin_bit_cast(short8, r);
}

// scales [N][ng] -> [ng][N] (write-coalesced)
__global__ __launch_bounds__(256)
void strans_kernel(const float* __restrict__ sc, float* __restrict__ sct, int N, int ng) {
    int n = blockIdx.x * 256 + threadIdx.x;
    int g = blockIdx.y;
    sct[(size_t)g * N + n] = sc[(size_t)n * ng + g];
}

__global__ __launch_bounds__(512, 4)
void int4mm_kernel(const unsigned short* __restrict__ xf,  // fp16 frag-ordered x
                   const int*   __restrict__ wp,           // [N][K/2]
                   const float* __restrict__ sct,          // [ng][N]
                   const float* __restrict__ bias,         // [N]
                   float*       __restrict__ out,          // [64][N]
                   int K, int N)
{
    __shared__ char ldsW[RING * 16384];      // 64 KB W ring (epilogue reuses)
    __shared__ int  prodDone[64];            // per-group staged waves (4 = full)
    __shared__ int  consDone[64];            // per-group consumed waves (4 = free)

    const int tid  = threadIdx.x;
    const int wave = tid >> 6;
    const int lane = tid & 63;
    const int quad = lane >> 4;
    const int l15  = lane & 15;
    const int blk64 = blockIdx.x * 64;
    const int ng   = K / 128;                // 64 groups

    if (tid < 64) { prodDone[tid] = 0; consDone[tid] = 0; }

    f32x4 acc[4][4];
    #pragma unroll
    for (int mt = 0; mt < 4; ++mt)
        #pragma unroll
        for (int nt = 0; nt < 4; ++nt)
            acc[mt][nt] = f32x4{0.f, 0.f, 0.f, 0.f};

    __syncthreads();                         // flags zeroed & visible

    if (wave < 4) {
        // ---------------- PRODUCER (waves 0-3): stream W, never compute ----
        const int p = wave;
        const char* wp8 = (const char*)wp;   // one col's W row = 16384 B
        // verified involution (R7-R16): instr j covers cols p*16+j*4+quad;
        // lane supplies global chunk l15^(j*4+quad); slot s of col c holds s^(c&15).
        unsigned woff[4];
        #pragma unroll
        for (int j = 0; j < 4; ++j) {
            const int cloc  = p * 16 + j * 4 + quad;
            const int chunk = l15 ^ (j * 4 + quad);
            woff[j] = ((unsigned)(blk64 + cloc) << 14) + ((unsigned)chunk << 4);
        }
        #pragma unroll 1
        for (int g = 0; g < ng; ++g) {
            if (g >= RING) {                 // ring slot recycled: g-4 consumed?
                while (__hip_atomic_load(&consDone[g - RING], __ATOMIC_ACQUIRE,
                                         __HIP_MEMORY_SCOPE_WORKGROUP) < 4)
                    __builtin_amdgcn_s_sleep(1);
            }
            char* slot = ldsW + (size_t)(g & (RING - 1)) * 16384;
            #pragma unroll
            for (int j = 0; j < 4; ++j)
                gload_lds16(wp8 + woff[j] + (size_t)g * 256,
                            slot + (p * 4 + j) * 1024);
            // 2 groups (8 loads) in flight; g-2's 4 loads forced complete.
            asm volatile("s_waitcnt vmcnt(8)" ::: "memory");
            if (g >= 2) signal1(&prodDone[g - 2], lane);
        }
        asm volatile("s_waitcnt vmcnt(4)" ::: "memory");
        signal1(&prodDone[ng - 2], lane);
        asm volatile("s_waitcnt vmcnt(0)" ::: "memory");
        signal1(&prodDone[ng - 1], lane);
    } else {
        // ---------------- CONSUMER (waves 4-7): kstep-split compute --------
        const int kst = wave - 4;            // k-quarter owner (as R11)
        const int q   = kst * 4 + quad;
        int rdW[4];                          // beat-optimal swizzled reads
        #pragma unroll
        for (int nt = 0; nt < 4; ++nt)
            rdW[nt] = (nt * 16 + l15) * 256 + ((q ^ l15) << 4);

        const char* xbase = (const char*)xf + kst * 4096 + lane * 16;
        f16x8 xn[4];
        #pragma unroll
        for (int mt = 0; mt < 4; ++mt)       // X(0) -> regs
            xn[mt] = *(const f16x8*)(xbase + mt * 1024);

        float sfn[4], sfu[4];
        #pragma unroll
        for (int nt = 0; nt < 4; ++nt)       // sc(0)
            sfn[nt] = sct[blk64 + nt * 16 + l15];

        #pragma unroll 1
        for (int g = 0; g < ng; ++g) {
            const int gn = (g + 1 < ng) ? g + 1 : ng - 1;

            while (__hip_atomic_load(&prodDone[g], __ATOMIC_ACQUIRE,
                                     __HIP_MEMORY_SCOPE_WORKGROUP) < 4)
                __builtin_amdgcn_s_sleep(1);
            __builtin_amdgcn_sched_barrier(0);   // keep ds_reads below acquire

            const char* wb = ldsW + (size_t)(g & (RING - 1)) * 16384;
            i32x4 v0 = *(const i32x4*)(wb + rdW[0]);
            i32x4 v1 = *(const i32x4*)(wb + rdW[1]);
            i32x4 v2 = *(const i32x4*)(wb + rdW[2]);
            i32x4 v3 = *(const i32x4*)(wb + rdW[3]);

            #pragma unroll
            for (int nt = 0; nt < 4; ++nt) sfu[nt] = sfn[nt];
            const float* sp = sct + (size_t)gn * N + blk64;   // prefetch sc(g+1)
            #pragma unroll
            for (int nt = 0; nt < 4; ++nt)
                sfn[nt] = sp[nt * 16 + l15];

            {
                f16x8 b = dequant(v0, f16x2{(_Float16)sfu[0], (_Float16)sfu[0]});
                #pragma unroll
                for (int mt = 0; mt < 4; ++mt)
                    acc[mt][0] = __builtin_amdgcn_mfma_f32_16x16x32_f16(xn[mt], b, acc[mt][0], 0, 0, 0);
            }
            {
                f16x8 b = dequant(v1, f16x2{(_Float16)sfu[1], (_Float16)sfu[1]});
                #pragma unroll
                for (int mt = 0; mt < 4; ++mt)
                    acc[mt][1] = __builtin_amdgcn_mfma_f32_16x16x32_f16(xn[mt], b, acc[mt][1], 0, 0, 0);
            }
            {
                f16x8 b = dequant(v2, f16x2{(_Float16)sfu[2], (_Float16)sfu[2]});
                #pragma unroll
                for (int mt = 0; mt < 4; ++mt)
                    acc[mt][2] = __builtin_amdgcn_mfma_f32_16x16x32_f16(xn[mt], b, acc[mt][2], 0, 0, 0);
            }
            {
                f16x8 b = dequant(v3, f16x2{(_Float16)sfu[3], (_Float16)sfu[3]});
                #pragma unroll
                for (int mt = 0; mt < 4; ++mt)
                    acc[mt][3] = __builtin_amdgcn_mfma_f32_16x16x32_f16(xn[mt], b, acc[mt][3], 0, 0, 0);
            }

            // slot free: ds_reads (v0-v3) retired before the release-add
            asm volatile("s_waitcnt lgkmcnt(0)" ::: "memory");
            signal1(&consDone[g], lane);

            // reload X after all MFMAs using xn issued (anti-dep; ~full period
            // of L2 latency cover before next use)
            const char* xs = xbase + (size_t)gn * 16384;
            #pragma unroll
            for (int mt = 0; mt < 4; ++mt)
                xn[mt] = *(const f16x8*)(xs + mt * 1024);
        }
    }

    // ---- epilogue: cross-wave (kstep) reduce among consumer waves. ----
    __syncthreads();
    if (wave >= 4) {
        const int kst = wave - 4;
        #pragma unroll
        for (int o = 0; o < 4; ++o) {
            if (o == kst) continue;          // wave-uniform branch
            const int s = kst - (kst > o ? 1 : 0);
            #pragma unroll
            for (int nt = 0; nt < 4; ++nt)
                *(f32x4*)(ldsW + (size_t)(((o * 3 + s) * 4 + nt) * 1024) + lane * 16)
                    = acc[o][nt];
        }
    }
    __syncthreads();
    if (wave >= 4) {
        const int kst = wave - 4;
        f32x4 own[4];
        #pragma unroll
        for (int nt = 0; nt < 4; ++nt) own[nt] = acc[0][nt];
        #pragma unroll
        for (int o = 1; o < 4; ++o)
            if (kst == o) {                  // wave-uniform, compile-time idx
                own[0] = acc[o][0]; own[1] = acc[o][1];
                own[2] = acc[o][2]; own[3] = acc[o][3];
            }
        #pragma unroll
        for (int s = 0; s < 3; ++s)
            #pragma unroll
            for (int nt = 0; nt < 4; ++nt)
                own[nt] += *(const f32x4*)(ldsW + (size_t)(((kst * 3 + s) * 4 + nt) * 1024)
                                           + lane * 16);
        #pragma unroll
        for (int nt = 0; nt < 4; ++nt) {
            const int col = blk64 + nt * 16 + l15;
            const float bv = bias[col];
            #pragma unroll
            for (int r = 0; r < 4; ++r)
                out[(size_t)(kst * 16 + quad * 4 + r) * N + col] = own[nt][r] + bv;
        }
    }
}

extern "C" void kernel_launch(void* const* d_in, const int* in_sizes, int n_in,
                              void* d_out, int out_size, void* d_ws, size_t ws_size,
                              hipStream_t stream)
{
    const float* x    = (const float*)d_in[0];
    const int*   wp   = (const int*)d_in[1];
    const float* sc   = (const float*)d_in[2];
    const float* bias = (const float*)d_in[3];
    float*       out  = (float*)d_out;

    const int N  = in_sizes[3];                       // 28672
    const long long Kh = (long long)in_sizes[1] / N;  // 4096
    const int K  = (int)(2 * Kh);                     // 8192
    const int ng = K / 128;                           // 64

    unsigned short* xf = (unsigned short*)d_ws;       // 1 MB frag-ordered fp16 x
    const size_t xf_bytes = (size_t)ng * 16384;
    float* sct = (float*)((char*)d_ws + xf_bytes);    // 7.3 MB transposed scales

    xpack_kernel<<<(ng * 1024) / 256, 256, 0, stream>>>(x, xf, K);
    strans_kernel<<<dim3(N / 256, ng), 256, 0, stream>>>(sc, sct, N, ng);
    int4mm_kernel<<<N / 64, 512, 0, stream>>>(xf, wp, sct, bias, out, K, N);
}

// Round 19
// 97.333 us; speedup vs baseline: 1.8274x; 1.3520x over previous
//
#include <hip/hip_runtime.h>
#include <stdint.h>

// int4 grouped-quant GEMM: out[64][28672] = x[64][8192] . W^T + bias
// W packed [N][K/2] int32, one byte/int32 = 2 nibbles (low = even k), zp = 8,
// per-128-k scales. fp16 ref -> harness gives x/scales/bias/out as FP32.
// Round-19: R14 (best, 104.5 us) + NONTEMPORAL cache policy (aux=NT) on the
// W global_load_lds DMA. W is a 470 MB once-read stream (100% L2 miss) that
// currently thrashes the 4 MB per-XCD L2 (evicting the shared 1 MB xf) and
// competes for fill ports; NT marks it evict-first. Single-variable test:
// everything else identical to R14 (superstep-2, kstep-split waves, X-in-regs,
// involution-swizzled staging, counted vmcnt never 0).

typedef __attribute__((ext_vector_type(8))) short     short8;
typedef __attribute__((ext_vector_type(4))) float     f32x4;
typedef __attribute__((ext_vector_type(4))) int       i32x4;
typedef __attribute__((ext_vector_type(2))) _Float16  f16x2;
typedef __attribute__((ext_vector_type(8))) _Float16  f16x8;

// async global->LDS, 16 B/lane, default policy (cached) — for X-like data.
static __device__ __forceinline__ void gload_lds16(const void* gp, void* lp) {
    __builtin_amdgcn_global_load_lds(
        (const __attribute__((address_space(1))) unsigned int*)gp,
        (__attribute__((address_space(3))) unsigned int*)lp, 16, 0, 0);
}
// nontemporal variant (CPol NT bit, gfx9: 1<<1) — for the once-read W stream.
static __device__ __forceinline__ void gload_lds16_nt(const void* gp, void* lp) {
    __builtin_amdgcn_global_load_lds(
        (const __attribute__((address_space(1))) unsigned int*)gp,
        (__attribute__((address_space(3))) unsigned int*)lp, 16, 0, 2);
}

// int4 pair -> fp16 pair: u = 0x6400|nib (fp16 1024+v, exact), (u-1032) exact
// in f16 (= v-8), then *s (single rounding - matches reference fp16 mul).
static __device__ __forceinline__ f16x8 dequant(const i32x4& w, f16x2 s2) {
    const f16x2 c1032 = {(_Float16)1032.0f, (_Float16)1032.0f};
    union { unsigned u[4]; f16x8 v; } r;
    #pragma unroll
    for (int j = 0; j < 4; ++j) {
        unsigned v = (unsigned)w[j];
        unsigned u = ((v & 0xFu) | 0x64006400u) | ((v << 12) & 0xF0000u);
        f16x2 h = __builtin_bit_cast(f16x2, u);
        h = (h - c1032) * s2;
        r.u[j] = __builtin_bit_cast(unsigned, h);
    }
    return r.v;
}

// x fp32 [64][K] -> fp16 (lossless) in A-fragment order: xf[g][st][mt][lane][8]
__global__ __launch_bounds__(256)
void xpack_kernel(const float* __restrict__ x, unsigned short* __restrict__ xf, int K) {
    int c    = blockIdx.x * 256 + threadIdx.x;
    int g    = c >> 10;
    int st   = (c >> 8) & 3;
    int mt   = (c >> 6) & 3;
    int lane = c & 63;
    int quad = lane >> 4, l15 = lane & 15;
    const float* p = x + (size_t)(l15 + mt * 16) * K + g * 128 + st * 32 + quad * 8;
    f32x4 lo = *(const f32x4*)p;
    f32x4 hi = *(const f32x4*)(p + 4);
    f16x8 r = { (_Float16)lo[0], (_Float16)lo[1], (_Float16)lo[2], (_Float16)lo[3],
                (_Float16)hi[0], (_Float16)hi[1], (_Float16)hi[2], (_Float16)hi[3] };
    *(short8*)(xf + (size_t)c * 8) = __builtin_bit_cast(short8, r);
}

__global__ __launch_bounds__(256, 2)
void int4mm_kernel(const unsigned short* __restrict__ xf,  // fp16 frag-ordered x
                   const int*   __restrict__ wp,           // [N][K/2]
                   const float* __restrict__ sc,           // [N][ng]
                   const float* __restrict__ bias,         // [N]
                   float*       __restrict__ out,          // [64][N]
                   int K, int N)
{
    __shared__ char lds[81920];              // 64 KB W dbuf | 16 KB scales
    char*  ldsW = lds;                       // [2][64 col][32 slot][16 B]
    float* ldsS = (float*)(lds + 65536);     // [64 g][64 col]
    // (epilogue reuses ldsW for cross-wave partials, 48 KB)

    const int tid  = threadIdx.x;
    const int lane = tid & 63;
    const int wave = tid >> 6;               // kstep owner: k-quarter of each group
    const int quad = lane >> 4;
    const int l15  = lane & 15;
    const int blk64 = blockIdx.x * 64;
    const int ng   = K / 128;                // 64 groups
    const int ns   = ng / 2;                 // 32 supersteps (2 groups each)

    const char* wp8 = (const char*)wp;       // one col's W row = 16384 B

    // W stage sources (superstep = 512 B/col, 32 chunks): stage instr j of
    // wave w covers cols (w*8+j)*2 + (lane>>5); lane supplies global chunk
    // (lane&31) ^ (col&31); LDS slot t of col c holds chunk t ^ (c&31).
    unsigned woff[8];
    #pragma unroll
    for (int j = 0; j < 8; ++j) {
        const int cloc  = (wave * 8 + j) * 2 + (lane >> 5);
        const int chunk = (lane & 31) ^ (cloc & 31);
        woff[j] = ((unsigned)(blk64 + cloc) << 14) + ((unsigned)chunk << 4);
    }

    // B-frag ds_read offsets: col = nt*16+l15 (byte base col*512); group
    // parity e chunk = e*16 + q (q = wave*4+quad), stored at slot
    // (e^(nt&1))*16 + (q^l15) -> same verified 8-beat-optimal family.
    const int q = wave * 4 + quad;
    int rdA[4], rdB[4];
    #pragma unroll
    for (int nt = 0; nt < 4; ++nt) {
        const int base = (nt * 16 + l15) * 512 + ((q ^ l15) << 4);
        rdA[nt] = base + (((0 ^ (nt & 1)) * 16) << 4);
        rdB[nt] = base + (((1 ^ (nt & 1)) * 16) << 4);
    }

    // ---- prologue ----
    // scales: ldsS[g][c] = sc[(blk64+c)*ng + g] via 64 B contiguous loads.
    {
        const int c  = tid & 63;
        const int g0 = (tid >> 6) * 16;
        const float* sp = sc + (size_t)(blk64 + c) * ng + g0;
        f32x4 s0 = *(const f32x4*)(sp);
        f32x4 s1 = *(const f32x4*)(sp + 4);
        f32x4 s2 = *(const f32x4*)(sp + 8);
        f32x4 s3 = *(const f32x4*)(sp + 12);
        #pragma unroll
        for (int j = 0; j < 4; ++j) {
            ldsS[(g0 + 0  + j) * 64 + c] = s0[j];
            ldsS[(g0 + 4  + j) * 64 + c] = s1[j];
            ldsS[(g0 + 8  + j) * 64 + c] = s2[j];
            ldsS[(g0 + 12 + j) * 64 + c] = s3[j];
        }
    }
    #pragma unroll
    for (int j = 0; j < 8; ++j)              // stage W superstep 0 -> buf0 (NT)
        gload_lds16_nt(wp8 + woff[j], ldsW + (wave * 8 + j) * 1024);

    const char* xbase = (const char*)xf + wave * 4096 + lane * 16;
    f16x8 xa[4], xb[4];
    #pragma unroll
    for (int mt = 0; mt < 4; ++mt)           // X(0), X(1) -> regs
        xa[mt] = *(const f16x8*)(xbase + mt * 1024);
    #pragma unroll
    for (int mt = 0; mt < 4; ++mt)
        xb[mt] = *(const f16x8*)(xbase + 16384 + mt * 1024);

    f32x4 acc[4][4];
    #pragma unroll
    for (int mt = 0; mt < 4; ++mt)
        #pragma unroll
        for (int nt = 0; nt < 4; ++nt)
            acc[mt][nt] = f32x4{0.f, 0.f, 0.f, 0.f};

    __syncthreads();   // prologue drain: scales + W(S0) + X(0,1) landed

    // Main loop over supersteps. Per-iter VMEM = 8 W stages + 4 xa + 4 xb = 16.
    // vmcnt(16) leaves {xa(2s), xb(2s+1), W(s+1)} (the 16 newest) in flight
    // and forces W(s) — issued one full superstep (~2 group-periods) ago —
    // complete. X regs are additionally guarded by the compiler's own waits.
    #pragma unroll 1
    for (int s = 0; s < ns; ++s) {
        const int p  = s & 1;
        const int sn = (s + 1 < ns) ? s + 1 : ns - 1;   // clamped dead tail
        const int gA = 2 * s, gB = 2 * s + 1;
        const int nA = (gA + 2 < ng) ? gA + 2 : ng - 1; // X prefetch targets
        const int nB = (gB + 2 < ng) ? gB + 2 : ng - 1;

        __builtin_amdgcn_s_barrier();        // superstep s-1 readers of buf[p^1] done

        #pragma unroll
        for (int j = 0; j < 8; ++j)          // stage W(s+1) -> buf[p^1] (NT)
            gload_lds16_nt(wp8 + woff[j] + (size_t)sn * 512,
                           ldsW + (p ^ 1) * 32768 + (wave * 8 + j) * 1024);

        asm volatile("s_waitcnt vmcnt(16)" ::: "memory");  // W(s) landed (mine)
        __builtin_amdgcn_s_barrier();                      // ...for all waves
        __builtin_amdgcn_sched_barrier(0);   // keep ds_reads below the sync

        const char* wb = ldsW + p * 32768;
        const float* sgA = ldsS + gA * 64;
        const float* sgB = ldsS + gB * 64;

        {   // group A = 2s (fragments xa)
            i32x4 v0 = *(const i32x4*)(wb + rdA[0]);
            i32x4 v1 = *(const i32x4*)(wb + rdA[1]);
            i32x4 v2 = *(const i32x4*)(wb + rdA[2]);
            i32x4 v3 = *(const i32x4*)(wb + rdA[3]);
            const float sf0 = sgA[l15], sf1 = sgA[16 + l15];
            const float sf2 = sgA[32 + l15], sf3 = sgA[48 + l15];
            f16x8 b0 = dequant(v0, f16x2{(_Float16)sf0, (_Float16)sf0});
            f16x8 b1 = dequant(v1, f16x2{(_Float16)sf1, (_Float16)sf1});
            f16x8 b2 = dequant(v2, f16x2{(_Float16)sf2, (_Float16)sf2});
            f16x8 b3 = dequant(v3, f16x2{(_Float16)sf3, (_Float16)sf3});
            #pragma unroll
            for (int mt = 0; mt < 4; ++mt) {
                acc[mt][0] = __builtin_amdgcn_mfma_f32_16x16x32_f16(xa[mt], b0, acc[mt][0], 0, 0, 0);
                acc[mt][1] = __builtin_amdgcn_mfma_f32_16x16x32_f16(xa[mt], b1, acc[mt][1], 0, 0, 0);
                acc[mt][2] = __builtin_amdgcn_mfma_f32_16x16x32_f16(xa[mt], b2, acc[mt][2], 0, 0, 0);
                acc[mt][3] = __builtin_amdgcn_mfma_f32_16x16x32_f16(xa[mt], b3, acc[mt][3], 0, 0, 0);
            }
            const char* xs = xbase + (size_t)nA * 16384;   // issue X(2s+2)
            #pragma unroll
            for (int mt = 0; mt < 4; ++mt)
                xa[mt] = *(const f16x8*)(xs + mt * 1024);
        }
        {   // group B = 2s+1 (fragments xb)
            i32x4 v0 = *(const i32x4*)(wb + rdB[0]);
            i32x4 v1 = *(const i32x4*)(wb + rdB[1]);
            i32x4 v2 = *(const i32x4*)(wb + rdB[2]);
            i32x4 v3 = *(const i32x4*)(wb + rdB[3]);
            const float sf0 = sgB[l15], sf1 = sgB[16 + l15];
            const float sf2 = sgB[32 + l15], sf3 = sgB[48 + l15];
            f16x8 b0 = dequant(v0, f16x2{(_Float16)sf0, (_Float16)sf0});
            f16x8 b1 = dequant(v1, f16x2{(_Float16)sf1, (_Float16)sf1});
            f16x8 b2 = dequant(v2, f16x2{(_Float16)sf2, (_Float16)sf2});
            f16x8 b3 = dequant(v3, f16x2{(_Float16)sf3, (_Float16)sf3});
            #pragma unroll
            for (int mt = 0; mt < 4; ++mt) {
                acc[mt][0] = __builtin_amdgcn_mfma_f32_16x16x32_f16(xb[mt], b0, acc[mt][0], 0, 0, 0);
                acc[mt][1] = __builtin_amdgcn_mfma_f32_16x16x32_f16(xb[mt], b1, acc[mt][1], 0, 0, 0);
                acc[mt][2] = __builtin_amdgcn_mfma_f32_16x16x32_f16(xb[mt], b2, acc[mt][2], 0, 0, 0);
                acc[mt][3] = __builtin_amdgcn_mfma_f32_16x16x32_f16(xb[mt], b3, acc[mt][3], 0, 0, 0);
            }
            const char* xs = xbase + (size_t)nB * 16384;   // issue X(2s+3)
            #pragma unroll
            for (int mt = 0; mt < 4; ++mt)
                xb[mt] = *(const f16x8*)(xs + mt * 1024);
        }
    }

    // ---- epilogue: cross-wave (kstep) reduce. Wave w owns mt = w. ----
    // Partials: addr(owner o, slot s, nt) = ((o*3+s)*4+nt)*1024 + lane*16 (48 KB).
    __syncthreads();
    #pragma unroll
    for (int o = 0; o < 4; ++o) {
        if (o == wave) continue;             // wave-uniform branch
        const int s = wave - (wave > o ? 1 : 0);
        #pragma unroll
        for (int nt = 0; nt < 4; ++nt)
            *(f32x4*)(lds + (size_t)(((o * 3 + s) * 4 + nt) * 1024) + lane * 16)
                = acc[o][nt];
    }
    __syncthreads();

    f32x4 own[4];
    #pragma unroll
    for (int nt = 0; nt < 4; ++nt) own[nt] = acc[0][nt];
    #pragma unroll
    for (int o = 1; o < 4; ++o)
        if (wave == o) {                     // wave-uniform, compile-time acc idx
            own[0] = acc[o][0]; own[1] = acc[o][1];
            own[2] = acc[o][2]; own[3] = acc[o][3];
        }
    #pragma unroll
    for (int s = 0; s < 3; ++s)
        #pragma unroll
        for (int nt = 0; nt < 4; ++nt)
            own[nt] += *(const f32x4*)(lds + (size_t)(((wave * 3 + s) * 4 + nt) * 1024)
                                       + lane * 16);

    #pragma unroll
    for (int nt = 0; nt < 4; ++nt) {
        const int col = blk64 + nt * 16 + l15;
        const float bv = bias[col];
        #pragma unroll
        for (int r = 0; r < 4; ++r)
            out[(size_t)(wave * 16 + quad * 4 + r) * N + col] = own[nt][r] + bv;
    }
}

extern "C" void kernel_launch(void* const* d_in, const int* in_sizes, int n_in,
                              void* d_out, int out_size, void* d_ws, size_t ws_size,
                              hipStream_t stream)
{
    const float* x    = (const float*)d_in[0];
    const int*   wp   = (const int*)d_in[1];
    const float* sc   = (const float*)d_in[2];
    const float* bias = (const float*)d_in[3];
    float*       out  = (float*)d_out;

    const int N  = in_sizes[3];                       // 28672
    const long long Kh = (long long)in_sizes[1] / N;  // 4096
    const int K  = (int)(2 * Kh);                     // 8192
    const int ng = K / 128;                           // 64

    unsigned short* xf = (unsigned short*)d_ws;       // 1 MB frag-ordered fp16 x

    xpack_kernel<<<(ng * 1024) / 256, 256, 0, stream>>>(x, xf, K);
    int4mm_kernel<<<N / 64, 256, 0, stream>>>(xf, wp, sc, bias, out, K, N);
}